// Round 7
// baseline (176.755 us; speedup 1.0000x reference)
//
#include <hip/hip_runtime.h>
#include <math.h>

#define N_TOK 4096
#define DMODEL 512
#define NH 8
#define HD 64

typedef __attribute__((ext_vector_type(4))) float f32x4;
typedef __attribute__((ext_vector_type(8))) _Float16 f16x8;
typedef __attribute__((ext_vector_type(4))) _Float16 f16x4;

#define MFMA16(A, B, C) __builtin_amdgcn_mfma_f32_16x16x32_f16(A, B, C, 0, 0, 0)

// XOR-swizzle for 64-col f16 tiles (validated in flash R2: conflicts 5.24M -> 0).
#define SWZ(r, c) (((r) * 64) + ((c) ^ (((r) & 7) << 3)))

// ---------------- fused cast + QKV GEMM: 768 thr, 12 waves, z-fused, dbuf -----
__global__ __launch_bounds__(768) void qkv_gemm(const float* __restrict__ x,
                                                const float* __restrict__ Wq,
                                                const float* __restrict__ bq,
                                                const float* __restrict__ Wk,
                                                const float* __restrict__ bk,
                                                const float* __restrict__ Wv,
                                                const float* __restrict__ bv,
                                                _Float16* __restrict__ Q16,
                                                _Float16* __restrict__ K16,
                                                _Float16* __restrict__ VT16) {
    // [0,16384): As[2][128][64] ; [16384,40960): Ws[2][3][64][64]  (80 KB)
    __shared__ __align__(16) _Float16 smem[40960];
    _Float16* AsB = smem;
    _Float16* WsB = smem + 16384;

    int t = threadIdx.x;
    int w = t >> 6, l = t & 63, quad = l >> 4, ln = l & 15;
    int z = w >> 2, ww = w & 3;
    int n0 = blockIdx.x * 128, o0 = blockIdx.y * 64;
    int h = o0 >> 6;

    const float* biasz = (z == 0) ? bq : (z == 1) ? bk : bv;

    f32x4 acc[2][4] = {};

    bool isA = (t < 256);
    int asr = t >> 3, asc = (t & 7) * 8;       // A staging (waves 0-3)
    int tt = t - 256;
    int wr = tt >> 3, wc = (tt & 7) * 8;       // W staging (waves 4-11)
    int axc = asc ^ ((asr & 7) << 3);          // swizzled A stage col
    int wxc = wc ^ ((wr & 7) << 3);            // swizzled W stage col

    const float* Abase = x + (size_t)n0 * DMODEL;
    const float* W0 = Wq + (size_t)o0 * DMODEL;
    const float* W1 = Wk + (size_t)o0 * DMODEL;
    const float* W2 = Wv + (size_t)o0 * DMODEL;

    // prefetch k0=0
    f32x4 pa[4][2];
    f32x4 pw[3][2];
    if (isA) {
#pragma unroll
        for (int r = 0; r < 4; r++) {
            pa[r][0] = *(const f32x4*)&Abase[(size_t)(asr + r * 32) * DMODEL + asc];
            pa[r][1] = *(const f32x4*)&Abase[(size_t)(asr + r * 32) * DMODEL + asc + 4];
        }
    } else {
        pw[0][0] = *(const f32x4*)&W0[(size_t)wr * DMODEL + wc];
        pw[0][1] = *(const f32x4*)&W0[(size_t)wr * DMODEL + wc + 4];
        pw[1][0] = *(const f32x4*)&W1[(size_t)wr * DMODEL + wc];
        pw[1][1] = *(const f32x4*)&W1[(size_t)wr * DMODEL + wc + 4];
        pw[2][0] = *(const f32x4*)&W2[(size_t)wr * DMODEL + wc];
        pw[2][1] = *(const f32x4*)&W2[(size_t)wr * DMODEL + wc + 4];
    }

    for (int it = 0; it < 8; it++) {
        int p = it & 1;
        if (isA) {
#pragma unroll
            for (int r = 0; r < 4; r++) {
                f16x8 av = {(_Float16)pa[r][0][0], (_Float16)pa[r][0][1],
                            (_Float16)pa[r][0][2], (_Float16)pa[r][0][3],
                            (_Float16)pa[r][1][0], (_Float16)pa[r][1][1],
                            (_Float16)pa[r][1][2], (_Float16)pa[r][1][3]};
                *(f16x8*)&AsB[(size_t)(p * 128 + asr + r * 32) * 64 + axc] = av;
            }
        } else {
#pragma unroll
            for (int zt = 0; zt < 3; zt++) {
                f16x8 wv_ = {(_Float16)pw[zt][0][0], (_Float16)pw[zt][0][1],
                             (_Float16)pw[zt][0][2], (_Float16)pw[zt][0][3],
                             (_Float16)pw[zt][1][0], (_Float16)pw[zt][1][1],
                             (_Float16)pw[zt][1][2], (_Float16)pw[zt][1][3]};
                *(f16x8*)&WsB[(size_t)((p * 3 + zt) * 64 + wr) * 64 + wxc] = wv_;
            }
        }
        __syncthreads();  // single barrier: write(it+1) after this; reads(it-1) before

        int k1 = (it + 1) * 64;
        if (k1 < DMODEL) {
            if (isA) {
#pragma unroll
                for (int r = 0; r < 4; r++) {
                    pa[r][0] = *(const f32x4*)&Abase[(size_t)(asr + r * 32) * DMODEL + k1 + asc];
                    pa[r][1] = *(const f32x4*)&Abase[(size_t)(asr + r * 32) * DMODEL + k1 + asc + 4];
                }
            } else {
                pw[0][0] = *(const f32x4*)&W0[(size_t)wr * DMODEL + k1 + wc];
                pw[0][1] = *(const f32x4*)&W0[(size_t)wr * DMODEL + k1 + wc + 4];
                pw[1][0] = *(const f32x4*)&W1[(size_t)wr * DMODEL + k1 + wc];
                pw[1][1] = *(const f32x4*)&W1[(size_t)wr * DMODEL + k1 + wc + 4];
                pw[2][0] = *(const f32x4*)&W2[(size_t)wr * DMODEL + k1 + wc];
                pw[2][1] = *(const f32x4*)&W2[(size_t)wr * DMODEL + k1 + wc + 4];
            }
        }

#pragma unroll
        for (int ks = 0; ks < 2; ks++) {
            int xc = (ks * 32 + quad * 8) ^ ((ln & 7) << 3);   // same for af & bf rows
            f16x8 af0 = *(const f16x8*)&AsB[(size_t)(p * 128 + ww * 32 + ln) * 64 + xc];
            f16x8 af1 = *(const f16x8*)&AsB[(size_t)(p * 128 + ww * 32 + 16 + ln) * 64 + xc];
#pragma unroll
            for (int c = 0; c < 4; c++) {
                f16x8 bf = *(const f16x8*)&WsB[(size_t)((p * 3 + z) * 64 + c * 16 + ln) * 64 + xc];
                acc[0][c] = MFMA16(af0, bf, acc[0][c]);
                acc[1][c] = MFMA16(af1, bf, acc[1][c]);
            }
        }
    }

    __syncthreads();  // all compute reads done before epilogue staging reuses LDS

    const float QS = 0.125f * 1.44269504088896340736f;  // fold log2e -> exp2 in flash
    _Float16* Qs = smem;             // 128x72
    _Float16* Ksep = smem + 9216;    // 128x72
    _Float16* Vt = smem + 18432;     // 64x136

    if (z < 2) {
        _Float16* st = (z == 0) ? Qs : Ksep;
        float sc_ = (z == 0) ? QS : 1.0f;
#pragma unroll
        for (int c = 0; c < 4; c++) {
            float bv_ = biasz[o0 + c * 16 + ln];
#pragma unroll
            for (int rt = 0; rt < 2; rt++)
#pragma unroll
                for (int i = 0; i < 4; i++) {
                    int lr = ww * 32 + rt * 16 + quad * 4 + i;
                    st[(size_t)lr * 72 + c * 16 + ln] =
                        (_Float16)((acc[rt][c][i] + bv_) * sc_);
                }
        }
    } else {
#pragma unroll
        for (int c = 0; c < 4; c++) {
            float bv_ = biasz[o0 + c * 16 + ln];
#pragma unroll
            for (int rt = 0; rt < 2; rt++)
#pragma unroll
                for (int i = 0; i < 4; i++) {
                    // token u64 = (ww&1)*32 + rt*16 + quad*4 + i in 64-group (ww>>1)
                    // stored at pos = sigma^-1(u64) = (ww&1)*32 + quad*8 + rt*4 + i
                    int np = (ww >> 1) * 64 + (ww & 1) * 32 + quad * 8 + rt * 4 + i;
                    Vt[(size_t)(c * 16 + ln) * 136 + np] = (_Float16)(acc[rt][c][i] + bv_);
                }
        }
    }
    __syncthreads();

    if (t < 256) {
#pragma unroll
        for (int k = 0; k < 4; k++) {
            int row = k * 32 + (t >> 3), col = (t & 7) * 8;
            *(f16x8*)&Q16[((size_t)h * N_TOK + n0 + row) * HD + col] =
                *(const f16x8*)&Qs[(size_t)row * 72 + col];
        }
    } else if (t < 512) {
        int u = t - 256;
#pragma unroll
        for (int k = 0; k < 4; k++) {
            int row = k * 32 + (u >> 3), col = (u & 7) * 8;
            *(f16x8*)&K16[((size_t)h * N_TOK + n0 + row) * HD + col] =
                *(const f16x8*)&Ksep[(size_t)row * 72 + col];
        }
    } else {
        int u = t - 512;
#pragma unroll
        for (int k = 0; k < 4; k++) {
            int d = k * 16 + (u >> 4), col = (u & 15) * 8;
            *(f16x8*)&VT16[((size_t)h * HD + d) * N_TOK + n0 + col] =
                *(const f16x8*)&Vt[(size_t)d * 136 + col];
        }
    }
}

// ---------------- flash attention, templated on split-K count NS --------------
// R17: NS=8 -> grid 512, 2 blocks/CU (8 waves/SIMD): independent barrier domains
// fill each other's stalls. Inner loop IDENTICAL to R6 (isolates occupancy).
// NS=4 instantiation == R6 exactly (ws fallback).
template <int NS>
__global__ __launch_bounds__(1024) void flash_mfma(const _Float16* __restrict__ Q16,
                                                   const _Float16* __restrict__ K16,
                                                   const _Float16* __restrict__ VT16,
                                                   _Float16* __restrict__ OP,
                                                   float* __restrict__ LS) {
    constexpr int ITERS = (N_TOK / NS) / 64;
    __shared__ __align__(16) _Float16 Ks[2][64 * 64];   // 16 KB
    __shared__ __align__(16) _Float16 Vs[2][64 * 64];   // 16 KB

    int t = threadIdx.x;
    int w = t >> 6, l = t & 63, quad = l >> 4, ln = l & 15;
    int bid = blockIdx.x;
    int h = bid & 7;
    int qt = (bid >> 3) & 7;
    int s = bid >> 6;
    int q0 = qt * 512 + w * 32;
    int m_start = s * (N_TOK / NS);

    f16x8 qf[2][2];
#pragma unroll
    for (int rt = 0; rt < 2; rt++) {
        const _Float16* qp = &Q16[((size_t)h * N_TOK + q0 + rt * 16 + ln) * HD + quad * 8];
        qf[rt][0] = *(const f16x8*)qp;
        qf[rt][1] = *(const f16x8*)(qp + 32);
    }

    f16x8 ones;
#pragma unroll
    for (int j = 0; j < 8; j++) ones[j] = (_Float16)1.0f;

    f32x4 oacc[2][4] = {};   // oacc[rt][c][i] = O[q=q0+rt*16+ln][d=c*16+quad*4+i]
    f32x4 lacc[2] = {};      // lacc[rt][i] = lsum[q=q0+rt*16+ln] (all i, all quads)

    const _Float16* kbase = K16 + (size_t)h * N_TOK * HD;
    const _Float16* vbase = VT16 + (size_t)h * HD * N_TOK;
    int g = t >> 9, tt = t & 511;
    int srow = tt >> 3, scol = (tt & 7) * 8;

    f16x8 pkv;
    if (g == 0)
        pkv = *(const f16x8*)(kbase + (size_t)(m_start + srow) * HD + scol);
    else
        pkv = *(const f16x8*)(vbase + (size_t)srow * N_TOK + m_start + scol);

    for (int it = 0; it < ITERS; it++) {
        int m0 = m_start + it * 64;
        int p = it & 1;
        if (g == 0)
            *(f16x8*)&Ks[p][SWZ(srow, scol)] = pkv;
        else
            *(f16x8*)&Vs[p][SWZ(srow, scol)] = pkv;
        __syncthreads();

        if (it < ITERS - 1) {
            int m1 = m0 + 64;
            if (g == 0)
                pkv = *(const f16x8*)(kbase + (size_t)(m1 + srow) * HD + scol);
            else
                pkv = *(const f16x8*)(vbase + (size_t)srow * N_TOK + m1 + scol);
        }

        f16x8 kb[4][2], vb[4][2];
#pragma unroll
        for (int c = 0; c < 4; c++) {
            kb[c][0] = *(const f16x8*)&Ks[p][SWZ(c * 16 + ln, quad * 8)];
            kb[c][1] = *(const f16x8*)&Ks[p][SWZ(c * 16 + ln, 32 + quad * 8)];
            vb[c][0] = *(const f16x8*)&Vs[p][SWZ(c * 16 + ln, quad * 8)];
            vb[c][1] = *(const f16x8*)&Vs[p][SWZ(c * 16 + ln, 32 + quad * 8)];
        }

        // swapped QK^T: sacc[kblk][i] = S[k=16*kblk+quad*4+i][q=rt*16+ln] (scaled)
        // P repack in-register: bf[rt][hh][j] = exp2(sacc[2hh + (j>>2)][j&3])
        f16x8 bf[2][2];
#pragma unroll
        for (int rt = 0; rt < 2; rt++) {
            f32x4 sacc[4] = {};
#pragma unroll
            for (int kk = 0; kk < 4; kk++) {
                sacc[kk] = MFMA16(kb[kk][0], qf[rt][0], sacc[kk]);
                sacc[kk] = MFMA16(kb[kk][1], qf[rt][1], sacc[kk]);
            }
#pragma unroll
            for (int kk = 0; kk < 4; kk++) {
                bf[rt][kk >> 1][(kk & 1) * 4 + 0] = (_Float16)__builtin_exp2f(sacc[kk][0]);
                bf[rt][kk >> 1][(kk & 1) * 4 + 1] = (_Float16)__builtin_exp2f(sacc[kk][1]);
                bf[rt][kk >> 1][(kk & 1) * 4 + 2] = (_Float16)__builtin_exp2f(sacc[kk][2]);
                bf[rt][kk >> 1][(kk & 1) * 4 + 3] = (_Float16)__builtin_exp2f(sacc[kk][3]);
            }
        }

        // lsum on the matrix pipe: lacc[rt] += ones^T x P
#pragma unroll
        for (int rt = 0; rt < 2; rt++) {
            lacc[rt] = MFMA16(ones, bf[rt][0], lacc[rt]);
            lacc[rt] = MFMA16(ones, bf[rt][1], lacc[rt]);
        }

        // PV (transposed): oacc[rt][c] += V^T-frag x P-frag
#pragma unroll
        for (int c = 0; c < 4; c++) {
            oacc[0][c] = MFMA16(vb[c][0], bf[0][0], oacc[0][c]);
            oacc[0][c] = MFMA16(vb[c][1], bf[0][1], oacc[0][c]);
            oacc[1][c] = MFMA16(vb[c][0], bf[1][0], oacc[1][c]);
            oacc[1][c] = MFMA16(vb[c][1], bf[1][1], oacc[1][c]);
        }
    }

    _Float16* obase = OP + (size_t)s * N_TOK * DMODEL;
#pragma unroll
    for (int rt = 0; rt < 2; rt++) {
        int r = q0 + rt * 16 + ln;
#pragma unroll
        for (int c = 0; c < 4; c++) {
            f16x4 ov = {(_Float16)oacc[rt][c][0], (_Float16)oacc[rt][c][1],
                        (_Float16)oacc[rt][c][2], (_Float16)oacc[rt][c][3]};
            *(f16x4*)&obase[(size_t)r * DMODEL + h * HD + c * 16 + quad * 4] = ov;
        }
    }
    if (l < 16) {   // quad==0 lanes; lacc[rt][0] holds the full split-local sum
#pragma unroll
        for (int rt = 0; rt < 2; rt++) {
            int r = q0 + rt * 16 + ln;
            LS[((size_t)s * NH + h) * N_TOK + r] = lacc[rt][0];
        }
    }
}

// ---------------- output GEMM, templated on NS: fused split-K combine, dbuf ----
template <int NS>
__global__ __launch_bounds__(512) void out_gemm(const _Float16* __restrict__ OP,
                                                const float* __restrict__ LS,
                                                const float* __restrict__ Wo,
                                                const float* __restrict__ bo,
                                                float* __restrict__ out) {
    // [0,16384): As[2][128][64] ; [16384,24576): Ws[2][64][64]  (48 KB)
    __shared__ __align__(16) _Float16 smem[24576];
    _Float16* AsB = smem;
    _Float16* WsB = smem + 16384;

    int t = threadIdx.x;
    int w = t >> 6, l = t & 63, quad = l >> 4, ln = l & 15;
    int n0 = blockIdx.x * 128, o0 = blockIdx.y * 64;
    int sr = t >> 2, sc = (t & 3) * 16;      // A: 1 row, 16 cols (2 f16x8)
    int wr = t >> 3, wc = (t & 7) * 8;       // W: 1 row, 8 floats
    int sxc0 = sc ^ ((sr & 7) << 3);         // swizzled A stage cols
    int sxc1 = (sc + 8) ^ ((sr & 7) << 3);
    int wxc = wc ^ ((wr & 7) << 3);          // swizzled W stage col
    const size_t PSTR = (size_t)N_TOK * DMODEL;

    f32x4 acc[4] = {};

    const float* Wbase = Wo + (size_t)o0 * DMODEL;

    // prefetch k0=0 (h=0)
    f16x8 pa[NS][2];
    float lt;
    f32x4 pw0, pw1;
    {
        size_t base = (size_t)(n0 + sr) * DMODEL + sc;
#pragma unroll
        for (int s_ = 0; s_ < NS; s_++) {
            pa[s_][0] = *(const f16x8*)&OP[s_ * PSTR + base];
            pa[s_][1] = *(const f16x8*)&OP[s_ * PSTR + base + 8];
        }
        const float* ls = LS + n0 + sr;   // h=0
        lt = 0.0f;
#pragma unroll
        for (int s_ = 0; s_ < NS; s_++) lt += ls[(size_t)s_ * NH * N_TOK];
        pw0 = *(const f32x4*)&Wbase[(size_t)wr * DMODEL + wc];
        pw1 = *(const f32x4*)&Wbase[(size_t)wr * DMODEL + wc + 4];
    }

    for (int it = 0; it < 8; it++) {
        int p = it & 1;
        {
            float inv = 1.0f / lt;
            f16x8 s0, s1;
#pragma unroll
            for (int j = 0; j < 8; j++) {
                float a0 = 0.0f, a1 = 0.0f;
#pragma unroll
                for (int s_ = 0; s_ < NS; s_++) {
                    a0 += (float)pa[s_][0][j];
                    a1 += (float)pa[s_][1][j];
                }
                s0[j] = (_Float16)(a0 * inv);
                s1[j] = (_Float16)(a1 * inv);
            }
            *(f16x8*)&AsB[(size_t)(p * 128 + sr) * 64 + sxc0] = s0;
            *(f16x8*)&AsB[(size_t)(p * 128 + sr) * 64 + sxc1] = s1;
            f16x8 wv_ = {(_Float16)pw0[0], (_Float16)pw0[1], (_Float16)pw0[2],
                         (_Float16)pw0[3], (_Float16)pw1[0], (_Float16)pw1[1],
                         (_Float16)pw1[2], (_Float16)pw1[3]};
            *(f16x8*)&WsB[(size_t)(p * 64 + wr) * 64 + wxc] = wv_;
        }
        __syncthreads();

        int k1 = (it + 1) * 64;
        if (k1 < DMODEL) {
            int h1 = k1 >> 6;
            size_t base = (size_t)(n0 + sr) * DMODEL + k1 + sc;
#pragma unroll
            for (int s_ = 0; s_ < NS; s_++) {
                pa[s_][0] = *(const f16x8*)&OP[s_ * PSTR + base];
                pa[s_][1] = *(const f16x8*)&OP[s_ * PSTR + base + 8];
            }
            const float* ls = LS + (size_t)h1 * N_TOK + n0 + sr;
            lt = 0.0f;
#pragma unroll
            for (int s_ = 0; s_ < NS; s_++) lt += ls[(size_t)s_ * NH * N_TOK];
            pw0 = *(const f32x4*)&Wbase[(size_t)wr * DMODEL + k1 + wc];
            pw1 = *(const f32x4*)&Wbase[(size_t)wr * DMODEL + k1 + wc + 4];
        }

#pragma unroll
        for (int ks = 0; ks < 2; ks++) {
            int xc = (ks * 32 + quad * 8) ^ ((ln & 7) << 3);
            f16x8 af = *(const f16x8*)&AsB[(size_t)(p * 128 + w * 16 + ln) * 64 + xc];
#pragma unroll
            for (int c = 0; c < 4; c++) {
                f16x8 bf = *(const f16x8*)&WsB[(size_t)(p * 64 + c * 16 + ln) * 64 + xc];
                acc[c] = MFMA16(af, bf, acc[c]);
            }
        }
    }

#pragma unroll
    for (int c = 0; c < 4; c++) {
        float bv_ = bo[o0 + c * 16 + ln];
#pragma unroll
        for (int i = 0; i < 4; i++) {
            int r = n0 + w * 16 + quad * 4 + i;
            out[(size_t)r * DMODEL + o0 + c * 16 + ln] = acc[c][i] + bv_;
        }
    }
}

extern "C" void kernel_launch(void* const* d_in, const int* in_sizes, int n_in,
                              void* d_out, int out_size, void* d_ws, size_t ws_size,
                              hipStream_t stream) {
    const float* x  = (const float*)d_in[0];
    const float* Wq = (const float*)d_in[1];
    const float* bq = (const float*)d_in[2];
    const float* Wk = (const float*)d_in[3];
    const float* bk = (const float*)d_in[4];
    const float* Wv = (const float*)d_in[5];
    const float* bv = (const float*)d_in[6];
    const float* Wo = (const float*)d_in[7];
    const float* bo = (const float*)d_in[8];
    float* out = (float*)d_out;

    char* ws = (char*)d_ws;
    _Float16* Q16  = (_Float16*)(ws);                    // 4 MB
    _Float16* K16  = (_Float16*)(ws + (4u << 20));       // 4 MB
    _Float16* VT16 = (_Float16*)(ws + (8u << 20));       // 4 MB (key-permuted, sigma)
    _Float16* OP   = (_Float16*)(ws + (12u << 20));      // NS x 4 MB split-K partials

    qkv_gemm<<<dim3(32, 8), 768, 0, stream>>>(x, Wq, bq, Wk, bk, Wv, bv,
                                              Q16, K16, VT16);

    if (ws_size >= ((size_t)46 << 20)) {
        // NS=8: OP 32 MB @12, LS 1 MB @44  (total 45 MB)
        float* LSp = (float*)(ws + (44u << 20));
        flash_mfma<8><<<dim3(512), 1024, 0, stream>>>(Q16, K16, VT16, OP, LSp);
        out_gemm<8><<<dim3(32, 8), 512, 0, stream>>>(OP, LSp, Wo, bo, out);
    } else {
        // NS=4 fallback (== R6): OP 16 MB @12, LS 0.5 MB @28  (total 28.5 MB)
        float* LSp = (float*)(ws + (28u << 20));
        flash_mfma<4><<<dim3(256), 1024, 0, stream>>>(Q16, K16, VT16, OP, LSp);
        out_gemm<4><<<dim3(32, 8), 512, 0, stream>>>(OP, LSp, Wo, bo, out);
    }
}

// Round 8
// 147.675 us; speedup vs baseline: 1.1969x; 1.1969x over previous
//
#include <hip/hip_runtime.h>
#include <math.h>

#define N_TOK 4096
#define DMODEL 512
#define NH 8
#define HD 64

typedef __attribute__((ext_vector_type(4))) float f32x4;
typedef __attribute__((ext_vector_type(8))) _Float16 f16x8;
typedef __attribute__((ext_vector_type(4))) _Float16 f16x4;

#define MFMA16(A, B, C) __builtin_amdgcn_mfma_f32_16x16x32_f16(A, B, C, 0, 0, 0)

// XOR-swizzle for 64-col f16 tiles (validated in flash R2: conflicts 5.24M -> 0).
#define SWZ(r, c) (((r) * 64) + ((c) ^ (((r) & 7) << 3)))

// ---------------- fused cast + QKV GEMM: 768 thr, 12 waves, z-fused, dbuf -----
// (exact R6 code — proven 150.7 us config)
__global__ __launch_bounds__(768) void qkv_gemm(const float* __restrict__ x,
                                                const float* __restrict__ Wq,
                                                const float* __restrict__ bq,
                                                const float* __restrict__ Wk,
                                                const float* __restrict__ bk,
                                                const float* __restrict__ Wv,
                                                const float* __restrict__ bv,
                                                _Float16* __restrict__ Q16,
                                                _Float16* __restrict__ K16,
                                                _Float16* __restrict__ VT16) {
    // [0,16384): As[2][128][64] ; [16384,40960): Ws[2][3][64][64]  (80 KB)
    __shared__ __align__(16) _Float16 smem[40960];
    _Float16* AsB = smem;
    _Float16* WsB = smem + 16384;

    int t = threadIdx.x;
    int w = t >> 6, l = t & 63, quad = l >> 4, ln = l & 15;
    int z = w >> 2, ww = w & 3;
    int n0 = blockIdx.x * 128, o0 = blockIdx.y * 64;
    int h = o0 >> 6;

    const float* biasz = (z == 0) ? bq : (z == 1) ? bk : bv;

    f32x4 acc[2][4] = {};

    bool isA = (t < 256);
    int asr = t >> 3, asc = (t & 7) * 8;       // A staging (waves 0-3)
    int tt = t - 256;
    int wr = tt >> 3, wc = (tt & 7) * 8;       // W staging (waves 4-11)
    int axc = asc ^ ((asr & 7) << 3);          // swizzled A stage col
    int wxc = wc ^ ((wr & 7) << 3);            // swizzled W stage col

    const float* Abase = x + (size_t)n0 * DMODEL;
    const float* W0 = Wq + (size_t)o0 * DMODEL;
    const float* W1 = Wk + (size_t)o0 * DMODEL;
    const float* W2 = Wv + (size_t)o0 * DMODEL;

    // prefetch k0=0
    f32x4 pa[4][2];
    f32x4 pw[3][2];
    if (isA) {
#pragma unroll
        for (int r = 0; r < 4; r++) {
            pa[r][0] = *(const f32x4*)&Abase[(size_t)(asr + r * 32) * DMODEL + asc];
            pa[r][1] = *(const f32x4*)&Abase[(size_t)(asr + r * 32) * DMODEL + asc + 4];
        }
    } else {
        pw[0][0] = *(const f32x4*)&W0[(size_t)wr * DMODEL + wc];
        pw[0][1] = *(const f32x4*)&W0[(size_t)wr * DMODEL + wc + 4];
        pw[1][0] = *(const f32x4*)&W1[(size_t)wr * DMODEL + wc];
        pw[1][1] = *(const f32x4*)&W1[(size_t)wr * DMODEL + wc + 4];
        pw[2][0] = *(const f32x4*)&W2[(size_t)wr * DMODEL + wc];
        pw[2][1] = *(const f32x4*)&W2[(size_t)wr * DMODEL + wc + 4];
    }

    for (int it = 0; it < 8; it++) {
        int p = it & 1;
        if (isA) {
#pragma unroll
            for (int r = 0; r < 4; r++) {
                f16x8 av = {(_Float16)pa[r][0][0], (_Float16)pa[r][0][1],
                            (_Float16)pa[r][0][2], (_Float16)pa[r][0][3],
                            (_Float16)pa[r][1][0], (_Float16)pa[r][1][1],
                            (_Float16)pa[r][1][2], (_Float16)pa[r][1][3]};
                *(f16x8*)&AsB[(size_t)(p * 128 + asr + r * 32) * 64 + axc] = av;
            }
        } else {
#pragma unroll
            for (int zt = 0; zt < 3; zt++) {
                f16x8 wv_ = {(_Float16)pw[zt][0][0], (_Float16)pw[zt][0][1],
                             (_Float16)pw[zt][0][2], (_Float16)pw[zt][0][3],
                             (_Float16)pw[zt][1][0], (_Float16)pw[zt][1][1],
                             (_Float16)pw[zt][1][2], (_Float16)pw[zt][1][3]};
                *(f16x8*)&WsB[(size_t)((p * 3 + zt) * 64 + wr) * 64 + wxc] = wv_;
            }
        }
        __syncthreads();  // single barrier: write(it+1) after this; reads(it-1) before

        int k1 = (it + 1) * 64;
        if (k1 < DMODEL) {
            if (isA) {
#pragma unroll
                for (int r = 0; r < 4; r++) {
                    pa[r][0] = *(const f32x4*)&Abase[(size_t)(asr + r * 32) * DMODEL + k1 + asc];
                    pa[r][1] = *(const f32x4*)&Abase[(size_t)(asr + r * 32) * DMODEL + k1 + asc + 4];
                }
            } else {
                pw[0][0] = *(const f32x4*)&W0[(size_t)wr * DMODEL + k1 + wc];
                pw[0][1] = *(const f32x4*)&W0[(size_t)wr * DMODEL + k1 + wc + 4];
                pw[1][0] = *(const f32x4*)&W1[(size_t)wr * DMODEL + k1 + wc];
                pw[1][1] = *(const f32x4*)&W1[(size_t)wr * DMODEL + k1 + wc + 4];
                pw[2][0] = *(const f32x4*)&W2[(size_t)wr * DMODEL + k1 + wc];
                pw[2][1] = *(const f32x4*)&W2[(size_t)wr * DMODEL + k1 + wc + 4];
            }
        }

#pragma unroll
        for (int ks = 0; ks < 2; ks++) {
            int xc = (ks * 32 + quad * 8) ^ ((ln & 7) << 3);   // same for af & bf rows
            f16x8 af0 = *(const f16x8*)&AsB[(size_t)(p * 128 + ww * 32 + ln) * 64 + xc];
            f16x8 af1 = *(const f16x8*)&AsB[(size_t)(p * 128 + ww * 32 + 16 + ln) * 64 + xc];
#pragma unroll
            for (int c = 0; c < 4; c++) {
                f16x8 bf = *(const f16x8*)&WsB[(size_t)((p * 3 + z) * 64 + c * 16 + ln) * 64 + xc];
                acc[0][c] = MFMA16(af0, bf, acc[0][c]);
                acc[1][c] = MFMA16(af1, bf, acc[1][c]);
            }
        }
    }

    __syncthreads();  // all compute reads done before epilogue staging reuses LDS

    const float QS = 0.125f * 1.44269504088896340736f;  // fold log2e -> exp2 in flash
    _Float16* Qs = smem;             // 128x72
    _Float16* Ksep = smem + 9216;    // 128x72
    _Float16* Vt = smem + 18432;     // 64x136

    if (z < 2) {
        _Float16* st = (z == 0) ? Qs : Ksep;
        float sc_ = (z == 0) ? QS : 1.0f;
#pragma unroll
        for (int c = 0; c < 4; c++) {
            float bv_ = biasz[o0 + c * 16 + ln];
#pragma unroll
            for (int rt = 0; rt < 2; rt++)
#pragma unroll
                for (int i = 0; i < 4; i++) {
                    int lr = ww * 32 + rt * 16 + quad * 4 + i;
                    st[(size_t)lr * 72 + c * 16 + ln] =
                        (_Float16)((acc[rt][c][i] + bv_) * sc_);
                }
        }
    } else {
#pragma unroll
        for (int c = 0; c < 4; c++) {
            float bv_ = biasz[o0 + c * 16 + ln];
#pragma unroll
            for (int rt = 0; rt < 2; rt++)
#pragma unroll
                for (int i = 0; i < 4; i++) {
                    // token u64 = (ww&1)*32 + rt*16 + quad*4 + i in 64-group (ww>>1)
                    // stored at pos = sigma^-1(u64) = (ww&1)*32 + quad*8 + rt*4 + i
                    int np = (ww >> 1) * 64 + (ww & 1) * 32 + quad * 8 + rt * 4 + i;
                    Vt[(size_t)(c * 16 + ln) * 136 + np] = (_Float16)(acc[rt][c][i] + bv_);
                }
        }
    }
    __syncthreads();

    if (t < 256) {
#pragma unroll
        for (int k = 0; k < 4; k++) {
            int row = k * 32 + (t >> 3), col = (t & 7) * 8;
            *(f16x8*)&Q16[((size_t)h * N_TOK + n0 + row) * HD + col] =
                *(const f16x8*)&Qs[(size_t)row * 72 + col];
        }
    } else if (t < 512) {
        int u = t - 256;
#pragma unroll
        for (int k = 0; k < 4; k++) {
            int row = k * 32 + (u >> 3), col = (u & 7) * 8;
            *(f16x8*)&K16[((size_t)h * N_TOK + n0 + row) * HD + col] =
                *(const f16x8*)&Ksep[(size_t)row * 72 + col];
        }
    } else {
        int u = t - 512;
#pragma unroll
        for (int k = 0; k < 4; k++) {
            int d = k * 16 + (u >> 4), col = (u & 15) * 8;
            *(f16x8*)&VT16[((size_t)h * HD + d) * N_TOK + n0 + col] =
                *(const f16x8*)&Vt[(size_t)d * 136 + col];
        }
    }
}

// ---------------- flash attention: 1024 thr, 16 waves x 32 rows ---------------
// R18: BK=128 keys/iter (two side-by-side 64-key sub-tiles, same SWZ) -> 8 iters,
// 9 barriers instead of 17. Inner body per kh is byte-identical to R6's; only
// fixed per-iteration cost (barrier drain) halves. NS=4 (R7 occupancy lever
// refuted: pipe-cycles constant, wall time +22%). No setprio (R5 spills).
__global__ __launch_bounds__(1024) void flash_mfma(const _Float16* __restrict__ Q16,
                                                   const _Float16* __restrict__ K16,
                                                   const _Float16* __restrict__ VT16,
                                                   _Float16* __restrict__ OP,
                                                   float* __restrict__ LS) {
    __shared__ __align__(16) _Float16 Ks[2][2][64 * 64];   // 32 KB
    __shared__ __align__(16) _Float16 Vs[2][2][64 * 64];   // 32 KB

    int t = threadIdx.x;
    int w = t >> 6, l = t & 63, quad = l >> 4, ln = l & 15;
    int bid = blockIdx.x;
    int h = bid & 7;
    int qt = (bid >> 3) & 7;
    int s = bid >> 6;
    int q0 = qt * 512 + w * 32;
    int m_start = s * 1024;

    f16x8 qf[2][2];
#pragma unroll
    for (int rt = 0; rt < 2; rt++) {
        const _Float16* qp = &Q16[((size_t)h * N_TOK + q0 + rt * 16 + ln) * HD + quad * 8];
        qf[rt][0] = *(const f16x8*)qp;
        qf[rt][1] = *(const f16x8*)(qp + 32);
    }

    f16x8 ones;
#pragma unroll
    for (int j = 0; j < 8; j++) ones[j] = (_Float16)1.0f;

    f32x4 oacc[2][4] = {};   // oacc[rt][c][i] = O[q=q0+rt*16+ln][d=c*16+quad*4+i]
    f32x4 lacc[2] = {};      // lacc[rt][i] = lsum[q=q0+rt*16+ln]

    const _Float16* kbase = K16 + (size_t)h * N_TOK * HD;
    const _Float16* vbase = VT16 + (size_t)h * HD * N_TOK;
    int g = t >> 9, tt = t & 511;
    // K stagers: 128 key-rows x 64 d; 2 f16x8/thread.
    int krow = tt >> 2, kcol = (tt & 3) * 16;
    // V stagers: 64 d-rows x 128 keys; 2 f16x8/thread.
    int vrow = tt >> 3, vcol = (tt & 7) * 16;

    f16x8 pk0, pk1;
    if (g == 0) {
        const _Float16* src = kbase + (size_t)(m_start + krow) * HD + kcol;
        pk0 = *(const f16x8*)src;
        pk1 = *(const f16x8*)(src + 8);
    } else {
        const _Float16* src = vbase + (size_t)vrow * N_TOK + m_start + vcol;
        pk0 = *(const f16x8*)src;
        pk1 = *(const f16x8*)(src + 8);
    }

    for (int it = 0; it < 8; it++) {
        int m0 = m_start + it * 128;
        int p = it & 1;
        if (g == 0) {
            _Float16* dst = &Ks[p][krow >> 6][0];
            int r64 = krow & 63;
            *(f16x8*)&dst[SWZ(r64, kcol)] = pk0;
            *(f16x8*)&dst[SWZ(r64, kcol + 8)] = pk1;
        } else {
            _Float16* dst = &Vs[p][vcol >> 6][0];
            int c64 = vcol & 63;
            *(f16x8*)&dst[SWZ(vrow, c64)] = pk0;
            *(f16x8*)&dst[SWZ(vrow, c64 + 8)] = pk1;
        }
        __syncthreads();

        if (it < 7) {
            int m1 = m0 + 128;
            if (g == 0) {
                const _Float16* src = kbase + (size_t)(m1 + krow) * HD + kcol;
                pk0 = *(const f16x8*)src;
                pk1 = *(const f16x8*)(src + 8);
            } else {
                const _Float16* src = vbase + (size_t)vrow * N_TOK + m1 + vcol;
                pk0 = *(const f16x8*)src;
                pk1 = *(const f16x8*)(src + 8);
            }
        }

#pragma unroll
        for (int kh = 0; kh < 2; kh++) {
            const _Float16* Kt = &Ks[p][kh][0];
            const _Float16* Vt = &Vs[p][kh][0];

            f16x8 kb[4][2], vb[4][2];
#pragma unroll
            for (int c = 0; c < 4; c++) {
                kb[c][0] = *(const f16x8*)&Kt[SWZ(c * 16 + ln, quad * 8)];
                kb[c][1] = *(const f16x8*)&Kt[SWZ(c * 16 + ln, 32 + quad * 8)];
                vb[c][0] = *(const f16x8*)&Vt[SWZ(c * 16 + ln, quad * 8)];
                vb[c][1] = *(const f16x8*)&Vt[SWZ(c * 16 + ln, 32 + quad * 8)];
            }

            // swapped QK^T: sacc[kblk][i] = S[k][q=rt*16+ln] (scaled); P repack in-reg
            f16x8 bf[2][2];
#pragma unroll
            for (int rt = 0; rt < 2; rt++) {
                f32x4 sacc[4] = {};
#pragma unroll
                for (int kk = 0; kk < 4; kk++) {
                    sacc[kk] = MFMA16(kb[kk][0], qf[rt][0], sacc[kk]);
                    sacc[kk] = MFMA16(kb[kk][1], qf[rt][1], sacc[kk]);
                }
#pragma unroll
                for (int kk = 0; kk < 4; kk++) {
                    bf[rt][kk >> 1][(kk & 1) * 4 + 0] = (_Float16)__builtin_exp2f(sacc[kk][0]);
                    bf[rt][kk >> 1][(kk & 1) * 4 + 1] = (_Float16)__builtin_exp2f(sacc[kk][1]);
                    bf[rt][kk >> 1][(kk & 1) * 4 + 2] = (_Float16)__builtin_exp2f(sacc[kk][2]);
                    bf[rt][kk >> 1][(kk & 1) * 4 + 3] = (_Float16)__builtin_exp2f(sacc[kk][3]);
                }
            }

            // lsum on the matrix pipe: lacc[rt] += ones^T x P
#pragma unroll
            for (int rt = 0; rt < 2; rt++) {
                lacc[rt] = MFMA16(ones, bf[rt][0], lacc[rt]);
                lacc[rt] = MFMA16(ones, bf[rt][1], lacc[rt]);
            }

            // PV (transposed): oacc[rt][c] += V^T-frag x P-frag
#pragma unroll
            for (int c = 0; c < 4; c++) {
                oacc[0][c] = MFMA16(vb[c][0], bf[0][0], oacc[0][c]);
                oacc[0][c] = MFMA16(vb[c][1], bf[0][1], oacc[0][c]);
                oacc[1][c] = MFMA16(vb[c][0], bf[1][0], oacc[1][c]);
                oacc[1][c] = MFMA16(vb[c][1], bf[1][1], oacc[1][c]);
            }
        }
    }

    _Float16* obase = OP + (size_t)s * N_TOK * DMODEL;
#pragma unroll
    for (int rt = 0; rt < 2; rt++) {
        int r = q0 + rt * 16 + ln;
#pragma unroll
        for (int c = 0; c < 4; c++) {
            f16x4 ov = {(_Float16)oacc[rt][c][0], (_Float16)oacc[rt][c][1],
                        (_Float16)oacc[rt][c][2], (_Float16)oacc[rt][c][3]};
            *(f16x4*)&obase[(size_t)r * DMODEL + h * HD + c * 16 + quad * 4] = ov;
        }
    }
    if (l < 16) {   // quad==0 lanes; lacc[rt][0] holds the full split-local sum
#pragma unroll
        for (int rt = 0; rt < 2; rt++) {
            int r = q0 + rt * 16 + ln;
            LS[((size_t)s * NH + h) * N_TOK + r] = lacc[rt][0];
        }
    }
}

// ---------------- output GEMM: 512 thr, BM=128, fused split-K combine, dbuf ----
// (exact R6 code)
__global__ __launch_bounds__(512) void out_gemm(const _Float16* __restrict__ OP,
                                                const float* __restrict__ LS,
                                                const float* __restrict__ Wo,
                                                const float* __restrict__ bo,
                                                float* __restrict__ out) {
    // [0,16384): As[2][128][64] ; [16384,24576): Ws[2][64][64]  (48 KB)
    __shared__ __align__(16) _Float16 smem[24576];
    _Float16* AsB = smem;
    _Float16* WsB = smem + 16384;

    int t = threadIdx.x;
    int w = t >> 6, l = t & 63, quad = l >> 4, ln = l & 15;
    int n0 = blockIdx.x * 128, o0 = blockIdx.y * 64;
    int sr = t >> 2, sc = (t & 3) * 16;      // A: 1 row, 16 cols (2 f16x8)
    int wr = t >> 3, wc = (t & 7) * 8;       // W: 1 row, 8 floats
    int sxc0 = sc ^ ((sr & 7) << 3);         // swizzled A stage cols
    int sxc1 = (sc + 8) ^ ((sr & 7) << 3);
    int wxc = wc ^ ((wr & 7) << 3);          // swizzled W stage col
    const size_t PSTR = (size_t)N_TOK * DMODEL;

    f32x4 acc[4] = {};

    const float* Wbase = Wo + (size_t)o0 * DMODEL;

    // prefetch k0=0 (h=0)
    f16x8 pa[4][2];
    float lt;
    f32x4 pw0, pw1;
    {
        size_t base = (size_t)(n0 + sr) * DMODEL + sc;
#pragma unroll
        for (int s_ = 0; s_ < 4; s_++) {
            pa[s_][0] = *(const f16x8*)&OP[s_ * PSTR + base];
            pa[s_][1] = *(const f16x8*)&OP[s_ * PSTR + base + 8];
        }
        const float* ls = LS + n0 + sr;   // h=0
        lt = (ls[0] + ls[NH * N_TOK]) + (ls[2 * NH * N_TOK] + ls[3 * NH * N_TOK]);
        pw0 = *(const f32x4*)&Wbase[(size_t)wr * DMODEL + wc];
        pw1 = *(const f32x4*)&Wbase[(size_t)wr * DMODEL + wc + 4];
    }

    for (int it = 0; it < 8; it++) {
        int p = it & 1;
        {
            float inv = 1.0f / lt;
            f16x8 s0, s1;
#pragma unroll
            for (int j = 0; j < 8; j++) {
                s0[j] = (_Float16)(
                    ((((float)pa[0][0][j] + (float)pa[1][0][j]) +
                      ((float)pa[2][0][j] + (float)pa[3][0][j]))) * inv);
                s1[j] = (_Float16)(
                    ((((float)pa[0][1][j] + (float)pa[1][1][j]) +
                      ((float)pa[2][1][j] + (float)pa[3][1][j]))) * inv);
            }
            *(f16x8*)&AsB[(size_t)(p * 128 + sr) * 64 + sxc0] = s0;
            *(f16x8*)&AsB[(size_t)(p * 128 + sr) * 64 + sxc1] = s1;
            f16x8 wv_ = {(_Float16)pw0[0], (_Float16)pw0[1], (_Float16)pw0[2],
                         (_Float16)pw0[3], (_Float16)pw1[0], (_Float16)pw1[1],
                         (_Float16)pw1[2], (_Float16)pw1[3]};
            *(f16x8*)&WsB[(size_t)(p * 64 + wr) * 64 + wxc] = wv_;
        }
        __syncthreads();

        int k1 = (it + 1) * 64;
        if (k1 < DMODEL) {
            int h1 = k1 >> 6;
            size_t base = (size_t)(n0 + sr) * DMODEL + k1 + sc;
#pragma unroll
            for (int s_ = 0; s_ < 4; s_++) {
                pa[s_][0] = *(const f16x8*)&OP[s_ * PSTR + base];
                pa[s_][1] = *(const f16x8*)&OP[s_ * PSTR + base + 8];
            }
            const float* ls = LS + (size_t)h1 * N_TOK + n0 + sr;
            lt = (ls[0] + ls[NH * N_TOK]) + (ls[2 * NH * N_TOK] + ls[3 * NH * N_TOK]);
            pw0 = *(const f32x4*)&Wbase[(size_t)wr * DMODEL + k1 + wc];
            pw1 = *(const f32x4*)&Wbase[(size_t)wr * DMODEL + k1 + wc + 4];
        }

#pragma unroll
        for (int ks = 0; ks < 2; ks++) {
            int xc = (ks * 32 + quad * 8) ^ ((ln & 7) << 3);
            f16x8 af = *(const f16x8*)&AsB[(size_t)(p * 128 + w * 16 + ln) * 64 + xc];
#pragma unroll
            for (int c = 0; c < 4; c++) {
                f16x8 bf = *(const f16x8*)&WsB[(size_t)(p * 64 + c * 16 + ln) * 64 + xc];
                acc[c] = MFMA16(af, bf, acc[c]);
            }
        }
    }

#pragma unroll
    for (int c = 0; c < 4; c++) {
        float bv_ = bo[o0 + c * 16 + ln];
#pragma unroll
        for (int i = 0; i < 4; i++) {
            int r = n0 + w * 16 + quad * 4 + i;
            out[(size_t)r * DMODEL + o0 + c * 16 + ln] = acc[c][i] + bv_;
        }
    }
}

extern "C" void kernel_launch(void* const* d_in, const int* in_sizes, int n_in,
                              void* d_out, int out_size, void* d_ws, size_t ws_size,
                              hipStream_t stream) {
    const float* x  = (const float*)d_in[0];
    const float* Wq = (const float*)d_in[1];
    const float* bq = (const float*)d_in[2];
    const float* Wk = (const float*)d_in[3];
    const float* bk = (const float*)d_in[4];
    const float* Wv = (const float*)d_in[5];
    const float* bv = (const float*)d_in[6];
    const float* Wo = (const float*)d_in[7];
    const float* bo = (const float*)d_in[8];
    float* out = (float*)d_out;

    char* ws = (char*)d_ws;
    _Float16* Q16  = (_Float16*)(ws + (4u << 20));       // 4 MB
    _Float16* K16  = (_Float16*)(ws + (8u << 20));       // 4 MB
    _Float16* VT16 = (_Float16*)(ws + (12u << 20));      // 4 MB (key-permuted, sigma)
    _Float16* OP   = (_Float16*)(ws + (16u << 20));      // 16 MB: 4 split-K partials
    float*    LSp  = (float*)   (ws + (32u << 20));      // 512 KB: [4][8][4096]
    // total 32.5 MB

    qkv_gemm<<<dim3(32, 8), 768, 0, stream>>>(x, Wq, bq, Wk, bk, Wv, bv,
                                              Q16, K16, VT16);

    flash_mfma<<<dim3(256), 1024, 0, stream>>>(Q16, K16, VT16, OP, LSp);

    out_gemm<<<dim3(32, 8), 512, 0, stream>>>(OP, LSp, Wo, bo, out);
}